// Round 5
// baseline (263.278 us; speedup 1.0000x reference)
//
#include <hip/hip_runtime.h>
#include <cstdint>

// Problem constants (B,S,D,H) from the reference
#define B_ 64
#define S_ 2048
#define D_ 512
#define H_ 512

using f32x4  = __attribute__((ext_vector_type(4))) float;
using bf16x8 = __attribute__((ext_vector_type(8))) short;

__device__ __forceinline__ unsigned short f2bf(float f) {
  unsigned u = __float_as_uint(f);
  u += 0x7FFFu + ((u >> 16) & 1u);   // round-to-nearest-even
  return (unsigned short)(u >> 16);
}
__device__ __forceinline__ float bf2f(unsigned short h) {
  return __uint_as_float(((unsigned)h) << 16);
}
// tanh via v_exp_f32: 1 - 2/(exp2(2x*log2e)+1); exact saturation at +-inf
__device__ __forceinline__ float fast_tanh(float x) {
  float t = __builtin_amdgcn_exp2f(x * 2.8853900817779268f);
  return 1.0f - 2.0f * __builtin_amdgcn_rcpf(t + 1.0f);
}

// async global->LDS, 16B per lane; LDS dest = wave-uniform base + lane*16
__device__ __forceinline__ void gl_lds16(const unsigned short* g, unsigned short* l) {
  __builtin_amdgcn_global_load_lds(
      (const __attribute__((address_space(1))) unsigned int*)g,
      (__attribute__((address_space(3))) unsigned int*)l, 16, 0, 0);
}

__device__ __forceinline__ void barrier_raw() {
  asm volatile("" ::: "memory");
  __builtin_amdgcn_s_barrier();
  asm volatile("" ::: "memory");
}

// ---------------------------------------------------------------------------
// fp32 -> bf16 pack, 8 elems/thread
__global__ void k_cvt(const float* __restrict__ src, unsigned short* __restrict__ dst, int n8) {
  int i = blockIdx.x * 256 + threadIdx.x;
  if (i >= n8) return;
  const f32x4* p = (const f32x4*)(src + (size_t)i * 8);
  f32x4 a = p[0], b = p[1];
  bf16x8 o;
  o[0] = (short)f2bf(a[0]); o[1] = (short)f2bf(a[1]);
  o[2] = (short)f2bf(a[2]); o[3] = (short)f2bf(a[3]);
  o[4] = (short)f2bf(b[0]); o[5] = (short)f2bf(b[1]);
  o[6] = (short)f2bf(b[2]); o[7] = (short)f2bf(b[3]);
  *(bf16x8*)(dst + (size_t)i * 8) = o;
}

// ---------------------------------------------------------------------------
// k_prep: blocks [0,128): di[b,h] = hidden[b,:].Wd[h,:] + bd[h]
//         blocks [128,256): We fp32 -> bf16 (32768 chunks of 8)
__global__ void k_prep(const float* __restrict__ hidden, const float* __restrict__ Wd,
                       const float* __restrict__ bd, float* __restrict__ di,
                       const float* __restrict__ We, unsigned short* __restrict__ Web) {
  if (blockIdx.x < 128) {
    int idx = blockIdx.x * 256 + threadIdx.x;   // 32768 total
    int h = idx >> 6;
    int b = idx & 63;
    const f32x4* hp = (const f32x4*)(hidden + (size_t)b * D_);
    const f32x4* wp = (const f32x4*)(Wd + (size_t)h * D_);
    float acc = 0.f;
#pragma unroll 8
    for (int i = 0; i < D_ / 4; ++i) {
      f32x4 x = hp[i], y = wp[i];
      acc += x[0] * y[0] + x[1] * y[1] + x[2] * y[2] + x[3] * y[3];
    }
    di[b * H_ + h] = acc + bd[h];
  } else {
    int i = (blockIdx.x - 128) * 256 + threadIdx.x;   // 32768 chunks
    const f32x4* p = (const f32x4*)(We + (size_t)i * 8);
    f32x4 a = p[0], b = p[1];
    bf16x8 o;
    o[0] = (short)f2bf(a[0]); o[1] = (short)f2bf(a[1]);
    o[2] = (short)f2bf(a[2]); o[3] = (short)f2bf(a[3]);
    o[4] = (short)f2bf(b[0]); o[5] = (short)f2bf(b[1]);
    o[6] = (short)f2bf(b[2]); o[7] = (short)f2bf(b[3]);
    *(bf16x8*)(Web + (size_t)i * 8) = o;
  }
}

// ---------------------------------------------------------------------------
// ei-GEMM with fused ui partials, atomic-free.
// A = ctx bf16 [131072 x 512], B = We bf16 [512 x 512].
// Tile 256x128, 8 waves (4M x 2N, 64x64 each), BK=64, 8 k-steps.
// Counted-vmcnt 2-tiles-in-flight pipeline, raw s_barrier (T3+T4), 98KB LDS,
// 1 block/CU (2 waves/SIMD, m201 regime).
//   prologue: STAGE(buf0,k0), STAGE(buf1,k1)     (6 gl_lds16/thread/tile)
//   iter kt:  vmcnt(6) -> tile kt resident (kt+1 stays in flight)
//             s_barrier; ds_read 16 frags; setprio(1) 32 MFMA setprio(0)
//             s_barrier; STAGE(buf[kt&1], kt+2)
// Rows are 128B (64 bf16) = 8 chunks of 16B; full XOR swizzle
// phys_chunk = logical ^ (row&7), applied on the per-lane GLOBAL source
// (gl_lds dest stays linear) and re-applied on ds_read -> 2-way banks (free).
__global__ __launch_bounds__(512, 2) void k_ei_gemm(
    const unsigned short* __restrict__ A, const unsigned short* __restrict__ Bw,
    const float* __restrict__ be, const float* __restrict__ V,
    const float* __restrict__ di, float* __restrict__ ui4) {
  __shared__ __align__(16) unsigned short ldsA[2][256 * 64];   // 64 KB
  __shared__ __align__(16) unsigned short ldsB[2][128 * 64];   // 32 KB
  __shared__ float ured[8][64];

  const int bid = blockIdx.x;
  const int swz = (bid & 7) * 256 + (bid >> 3);   // bijective XCD chunking (2048%8==0)
  const int row0 = (swz >> 2) << 8;               // 512 m-tiles of 256 rows
  const int nt   = swz & 3;
  const int col0 = nt << 7;

  const int t  = threadIdx.x;
  const int l  = t & 63;
  const int w  = t >> 6;          // 8 waves
  const int wm = (w >> 1) << 6;   // 4 M-bands of 64
  const int wn = (w & 1) << 6;    // 2 N-halves of 64
  const int lr = l & 15;
  const int lg = l >> 4;

  // staging: per gl_lds16 a wave writes 8 rows x 64 cols linearly.
  // lane l -> row +(l>>3), phys chunk l&7; source logical chunk (l&7)^((l>>3)&7).
  const int srow = w * 8 + (l >> 3);
  const int scol = ((l & 7) ^ ((l >> 3) & 7)) << 3;
  const unsigned short* srcA = A + (size_t)(row0 + srow) * D_ + scol;
  const unsigned short* srcB = Bw + (size_t)(col0 + srow) * D_ + scol;

#define STAGE(bf, kk) do {                                        \
    const unsigned short* a_ = srcA + ((kk) << 6);                \
    const unsigned short* b_ = srcB + ((kk) << 6);                \
    gl_lds16(a_,             &ldsA[bf][w * 512]);                 \
    gl_lds16(a_ + 64 * D_,   &ldsA[bf][4096 + w * 512]);          \
    gl_lds16(a_ + 128 * D_,  &ldsA[bf][8192 + w * 512]);          \
    gl_lds16(a_ + 192 * D_,  &ldsA[bf][12288 + w * 512]);         \
    gl_lds16(b_,             &ldsB[bf][w * 512]);                 \
    gl_lds16(b_ + 64 * D_,   &ldsB[bf][4096 + w * 512]);          \
  } while (0)

  // read-side: logical chunk kk*4+lg of row r -> phys (kk*4+lg)^(r&7); only lr
  // enters the XOR (wm/wn/mi*16 are multiples of 16). elem off = phys*8.
  const int rs0 = ((0 + lg) ^ (lr & 7)) << 3;   // kk=0
  const int rs1 = ((4 + lg) ^ (lr & 7)) << 3;   // kk=1

  f32x4 acc[4][4];
  const f32x4 z = {0.f, 0.f, 0.f, 0.f};
#pragma unroll
  for (int mi = 0; mi < 4; ++mi)
#pragma unroll
    for (int ni = 0; ni < 4; ++ni) acc[mi][ni] = z;

  STAGE(0, 0);
  STAGE(1, 1);

#define KSTEP(bf)                                                              \
  do {                                                                         \
    bf16x8 a0[4], b0[4], a1[4], b1[4];                                         \
    _Pragma("unroll") for (int mi = 0; mi < 4; ++mi) {                         \
      const int r_ = (wm + mi * 16 + lr) << 6;                                 \
      a0[mi] = *(const bf16x8*)&ldsA[bf][r_ + rs0];                            \
      a1[mi] = *(const bf16x8*)&ldsA[bf][r_ + rs1];                            \
    }                                                                          \
    _Pragma("unroll") for (int ni = 0; ni < 4; ++ni) {                         \
      const int r_ = (wn + ni * 16 + lr) << 6;                                 \
      b0[ni] = *(const bf16x8*)&ldsB[bf][r_ + rs0];                            \
      b1[ni] = *(const bf16x8*)&ldsB[bf][r_ + rs1];                            \
    }                                                                          \
    __builtin_amdgcn_s_setprio(1);                                             \
    _Pragma("unroll") for (int mi = 0; mi < 4; ++mi)                           \
        _Pragma("unroll") for (int ni = 0; ni < 4; ++ni)                       \
            acc[mi][ni] = __builtin_amdgcn_mfma_f32_16x16x32_bf16(             \
                a0[mi], b0[ni], acc[mi][ni], 0, 0, 0);                         \
    _Pragma("unroll") for (int mi = 0; mi < 4; ++mi)                           \
        _Pragma("unroll") for (int ni = 0; ni < 4; ++ni)                       \
            acc[mi][ni] = __builtin_amdgcn_mfma_f32_16x16x32_bf16(             \
                a1[mi], b1[ni], acc[mi][ni], 0, 0, 0);                         \
    __builtin_amdgcn_s_setprio(0);                                             \
  } while (0)

  for (int kt = 0; kt < 7; ++kt) {
    asm volatile("s_waitcnt vmcnt(6)" ::: "memory");   // tile kt resident; kt+1 in flight
    barrier_raw();
    KSTEP(kt & 1);
    barrier_raw();                                      // all reads of buf[kt&1] done
    if (kt < 6) STAGE(kt & 1, kt + 2);
  }
  asm volatile("s_waitcnt vmcnt(0)" ::: "memory");
  barrier_raw();
  KSTEP(1);
#undef KSTEP
#undef STAGE

  // fused ui partials over this block's 128 columns; atomic-free.
  // C/D layout: col = lr, row = lg*4 + j within each 16x16 frag.
  const int b = row0 >> 11;   // BM=256 divides S=2048 -> block-uniform batch
  float uacc[4][4];
#pragma unroll
  for (int mi = 0; mi < 4; ++mi)
#pragma unroll
    for (int j = 0; j < 4; ++j) uacc[mi][j] = 0.f;

#pragma unroll
  for (int ni = 0; ni < 4; ++ni) {
    const int gc = col0 + wn + ni * 16 + lr;
    const float vv = V[gc];
    const float base = di[b * H_ + gc] + be[gc];
#pragma unroll
    for (int mi = 0; mi < 4; ++mi)
#pragma unroll
      for (int j = 0; j < 4; ++j)
        uacc[mi][j] += vv * fast_tanh(base + acc[mi][ni][j]);
  }
  // reduce across the 16 lr-lanes; lanes lr==0 (lg=0..3) hold 4-row sums
#pragma unroll
  for (int mi = 0; mi < 4; ++mi)
#pragma unroll
    for (int j = 0; j < 4; ++j) {
      float s = uacc[mi][j];
      s += __shfl_xor(s, 1);
      s += __shfl_xor(s, 2);
      s += __shfl_xor(s, 4);
      s += __shfl_xor(s, 8);
      if (lr == 0) ured[w][mi * 16 + (lg << 2) + j] = s;
    }
  __syncthreads();
  if (t < 256) {
    const int band = t >> 6, r = t & 63;   // waves 2*band (wn=0) + 2*band+1 (wn=64)
    ui4[nt * (B_ * S_) + row0 + t] = ured[band * 2][r] + ured[band * 2 + 1][r];
  }
}

// ---------------------------------------------------------------------------
// softmax over S per batch row: sums the 4 ui partials, applies mask -> -inf.
// Mask dtype (bool-bytes vs int32) detected per block from word high-bytes
// (scan limited to first 128KB so it is in-bounds under both layouts).
__global__ void k_softmax(const float* __restrict__ ui4, const void* __restrict__ mask,
                          float* __restrict__ alpha) {
  __shared__ float red[4];
  __shared__ int sfl;
  const int b = blockIdx.x, t = threadIdx.x;
  const int l = t & 63, w = t >> 6;

  if (t == 0) sfl = 0;
  const unsigned int* mw = (const unsigned int*)mask;
  unsigned det = (mw[b * 512 + t] | mw[b * 512 + 256 + t]) & 0xFFFFFF00u;
  __syncthreads();
  if (det) atomicOr(&sfl, 1);
  __syncthreads();
  const int fl = sfl;   // 1 => byte layout

  float u[8];
#pragma unroll
  for (int i = 0; i < 8; ++i) {
    const int idx = b * S_ + t + i * 256;
    const int msk = fl ? (int)((const unsigned char*)mask)[idx]
                       : ((const int*)mask)[idx];
    const float uv = ui4[idx] + ui4[idx + B_ * S_] + ui4[idx + 2 * B_ * S_] +
                     ui4[idx + 3 * B_ * S_];
    u[i] = msk ? -__builtin_inff() : uv;
  }

  float mx = u[0];
#pragma unroll
  for (int i = 1; i < 8; ++i) mx = fmaxf(mx, u[i]);
#pragma unroll
  for (int off = 32; off; off >>= 1) mx = fmaxf(mx, __shfl_xor(mx, off));
  if (l == 0) red[w] = mx;
  __syncthreads();
  mx = fmaxf(fmaxf(red[0], red[1]), fmaxf(red[2], red[3]));
  __syncthreads();

  float p[8];
  float s = 0.f;
#pragma unroll
  for (int i = 0; i < 8; ++i) {
    p[i] = __builtin_amdgcn_exp2f((u[i] - mx) * 1.4426950408889634f);
    s += p[i];
  }
#pragma unroll
  for (int off = 32; off; off >>= 1) s += __shfl_xor(s, off);
  if (l == 0) red[w] = s;
  __syncthreads();
  s = red[0] + red[1] + red[2] + red[3];

  const float inv = 1.0f / s;
#pragma unroll
  for (int i = 0; i < 8; ++i) alpha[b * S_ + t + i * 256] = p[i] * inv;
}

// ---------------------------------------------------------------------------
// part[chunk][b][d] = sum over 128 s of alpha * ctxb   (atomic-free partials)
__global__ void k_wsum(const unsigned short* __restrict__ ctxb, const float* __restrict__ alpha,
                       float* __restrict__ part) {
  __shared__ float red[3][512];
  const int b = blockIdx.x >> 4, chunk = blockIdx.x & 15;
  const int t = threadIdx.x;
  const int h0 = (t & 63) << 3;
  const int sw = t >> 6;
  const int s0 = chunk << 7;

  float acc[8] = {0.f, 0.f, 0.f, 0.f, 0.f, 0.f, 0.f, 0.f};
#pragma unroll 4
  for (int k = 0; k < 32; ++k) {
    const int s = s0 + sw + (k << 2);
    const float a = alpha[b * S_ + s];
    bf16x8 e = *(const bf16x8*)(ctxb + ((size_t)(b * S_ + s)) * D_ + h0);
#pragma unroll
    for (int j = 0; j < 8; ++j) acc[j] += a * bf2f((unsigned short)e[j]);
  }
  if (sw) {
#pragma unroll
    for (int j = 0; j < 8; ++j) red[sw - 1][h0 + j] = acc[j];
  }
  __syncthreads();
  if (sw == 0) {
#pragma unroll
    for (int j = 0; j < 8; ++j)
      part[((chunk << 6) + b) * 512 + h0 + j] =
          acc[j] + red[0][h0 + j] + red[1][h0 + j] + red[2][h0 + j];
  }
}

// ---------------------------------------------------------------------------
// k_tail: one block per b (512 thr). Phase 1: collapse 16 part chunks into
// LDS wsum. Phase 2: out1[b,h] = wsum.We[h,:] + be[h] (We from L2/L3).
__global__ void k_tail(const float* __restrict__ part, const float* __restrict__ We,
                       const float* __restrict__ be, float* __restrict__ out1) {
  __shared__ float wsum_s[512];
  const int b = blockIdx.x, t = threadIdx.x;

  float s = 0.f;
#pragma unroll
  for (int c = 0; c < 16; ++c) s += part[((c << 6) + b) * 512 + t];
  wsum_s[t] = s;
  __syncthreads();

  const f32x4* wp = (const f32x4*)wsum_s;
  const f32x4* ep = (const f32x4*)(We + (size_t)t * D_);
  float acc = 0.f;
#pragma unroll 8
  for (int i = 0; i < D_ / 4; ++i) {
    f32x4 x = wp[i], y = ep[i];
    acc += x[0] * y[0] + x[1] * y[1] + x[2] * y[2] + x[3] * y[3];
  }
  out1[b * H_ + t] = acc + be[t];
}

// ---------------------------------------------------------------------------
extern "C" void kernel_launch(void* const* d_in, const int* in_sizes, int n_in,
                              void* d_out, int out_size, void* d_ws, size_t ws_size,
                              hipStream_t stream) {
  const float* hidden = (const float*)d_in[0];
  const float* ctx    = (const float*)d_in[1];
  const void*  mask   = d_in[2];
  const float* Wd     = (const float*)d_in[3];
  const float* bd     = (const float*)d_in[4];
  const float* We     = (const float*)d_in[5];
  const float* be     = (const float*)d_in[6];
  const float* V      = (const float*)d_in[7];

  float* out   = (float*)d_out;
  float* alpha = out;               // [B,S]
  float* out1  = out + B_ * S_;     // [B,H]

  // ws layout (regions reused across pipeline phases; everything written
  // before read, so no zero-init needed anywhere):
  //   [0, 134.2MB)  ctxb bf16
  //   [+2MB)        ui4 (gemm->softmax), then part (wsum->tail)
  //   [+128KB)      di (prep->gemm)
  //   [+512KB)      Web bf16
  char* ws = (char*)d_ws;
  const size_t off_ctxb = 0;
  const size_t off_u2   = off_ctxb + (size_t)B_ * S_ * D_ * 2;   // 134217728
  const size_t off_r3   = off_u2 + 4ull * B_ * S_ * 4;           // +2 MiB
  const size_t off_web  = off_r3 + (size_t)B_ * H_ * 4;          // +128 KiB

  unsigned short* ctxb = (unsigned short*)(ws + off_ctxb);
  float* ui4  = (float*)(ws + off_u2);
  float* part = (float*)(ws + off_u2);
  float* di   = (float*)(ws + off_r3);
  unsigned short* Web = (unsigned short*)(ws + off_web);

  k_cvt<<<(B_ * S_ * D_ / 8) / 256, 256, 0, stream>>>(ctx, ctxb, B_ * S_ * D_ / 8);
  k_prep<<<256, 256, 0, stream>>>(hidden, Wd, bd, di, We, Web);
  k_ei_gemm<<<(B_ * S_ / 256) * 4, 512, 0, stream>>>(ctxb, Web, be, V, di, ui4);
  k_softmax<<<B_, 256, 0, stream>>>(ui4, mask, alpha);
  k_wsum<<<B_ * 16, 256, 0, stream>>>(ctxb, alpha, part);
  k_tail<<<B_, 512, 0, stream>>>(part, We, be, out1);
}

// Round 6
// 208.270 us; speedup vs baseline: 1.2641x; 1.2641x over previous
//
#include <hip/hip_runtime.h>
#include <cstdint>

// Problem constants (B,S,D,H) from the reference
#define B_ 64
#define S_ 2048
#define D_ 512
#define H_ 512

using f32x4  = __attribute__((ext_vector_type(4))) float;
using bf16x8 = __attribute__((ext_vector_type(8))) short;
using u32x2  = __attribute__((ext_vector_type(2))) unsigned int;

__device__ __forceinline__ unsigned short f2bf(float f) {
  unsigned u = __float_as_uint(f);
  u += 0x7FFFu + ((u >> 16) & 1u);   // round-to-nearest-even
  return (unsigned short)(u >> 16);
}
// packed f32x2 -> bf16x2 (RTE), hardware op (T12 primitive; no builtin on gfx950)
__device__ __forceinline__ unsigned int cvtpk(float lo, float hi) {
  unsigned int r;
  asm("v_cvt_pk_bf16_f32 %0, %1, %2" : "=v"(r) : "v"(lo), "v"(hi));
  return r;
}
// tanh via v_exp_f32: 1 - 2/(exp2(2x*log2e)+1); exact saturation at +-inf
__device__ __forceinline__ float fast_tanh(float x) {
  float t = __builtin_amdgcn_exp2f(x * 2.8853900817779268f);
  return 1.0f - 2.0f * __builtin_amdgcn_rcpf(t + 1.0f);
}

__device__ __forceinline__ void barrier_raw() {
  asm volatile("" ::: "memory");
  __builtin_amdgcn_s_barrier();
  asm volatile("" ::: "memory");
}

// ---------------------------------------------------------------------------
// k_prep: blocks [0,128): di[b,h] = hidden[b,:].Wd[h,:] + bd[h]
//         blocks [128,256): We fp32 -> bf16 (32768 chunks of 8)
__global__ void k_prep(const float* __restrict__ hidden, const float* __restrict__ Wd,
                       const float* __restrict__ bd, float* __restrict__ di,
                       const float* __restrict__ We, unsigned short* __restrict__ Web) {
  if (blockIdx.x < 128) {
    int idx = blockIdx.x * 256 + threadIdx.x;   // 32768 total
    int h = idx >> 6;
    int b = idx & 63;
    const f32x4* hp = (const f32x4*)(hidden + (size_t)b * D_);
    const f32x4* wp = (const f32x4*)(Wd + (size_t)h * D_);
    float acc = 0.f;
#pragma unroll 8
    for (int i = 0; i < D_ / 4; ++i) {
      f32x4 x = hp[i], y = wp[i];
      acc += x[0] * y[0] + x[1] * y[1] + x[2] * y[2] + x[3] * y[3];
    }
    di[b * H_ + h] = acc + bd[h];
  } else {
    int i = (blockIdx.x - 128) * 256 + threadIdx.x;   // 32768 chunks
    const f32x4* p = (const f32x4*)(We + (size_t)i * 8);
    f32x4 a = p[0], b = p[1];
    bf16x8 o;
    o[0] = (short)f2bf(a[0]); o[1] = (short)f2bf(a[1]);
    o[2] = (short)f2bf(a[2]); o[3] = (short)f2bf(a[3]);
    o[4] = (short)f2bf(b[0]); o[5] = (short)f2bf(b[1]);
    o[6] = (short)f2bf(b[2]); o[7] = (short)f2bf(b[3]);
    *(bf16x8*)(Web + (size_t)i * 8) = o;
  }
}

// ---------------------------------------------------------------------------
// ei-GEMM, fp32 A read directly (no pre-converted ctx): reg-staged A with
// in-register v_cvt_pk_bf16_f32, reg-staged bf16 B. Fused ui partials.
// Tile 128x128, 4 waves (2x2), BK=32, 16 k-steps, 33KB LDS, 3 blocks/CU.
// Single-barrier pipeline (all VM ops are per-thread loads; compiler inserts
// minimal data-dep waitcnt; loads for tile kt+1 fly under tile kt's MFMA):
//   prologue: LOAD(0); WRITE(buf0); LOAD(1)
//   iter kt:  lgkmcnt(0); s_barrier        // buf[kt&1] ready for all waves;
//                                           // everyone's reads of buf[kt&1^1] retired
//             ds_read 8 frags from buf[kt&1]
//             WRITE(buf[kt&1^1])  <- tile kt+1 (waits own loads via data dep)
//             LOAD(kt+2)          <- in flight during MFMA + next iter
//             setprio(1); 16 MFMA; setprio(0)
// XOR slot swizzle (16B slots, phys = logical ^ ((row>>1)&3)) on both the
// ds_write and ds_read sides -> 2-way banks everywhere (free, m136).
__global__ __launch_bounds__(256, 3) void k_ei_gemm(
    const float* __restrict__ A, const unsigned short* __restrict__ Bw,
    const float* __restrict__ be, const float* __restrict__ V,
    const float* __restrict__ di, float* __restrict__ ui4) {
  __shared__ __align__(16) unsigned short ldsA[2][128 * 32];   // 8KB each
  __shared__ __align__(16) unsigned short ldsB[2][128 * 32];
  __shared__ float ured[4][64];

  const int bid = blockIdx.x;
  const int swz = (bid & 7) * 512 + (bid >> 3);   // bijective XCD chunking (4096%8==0)
  const int row0 = (swz >> 2) << 7;               // 1024 m-tiles of 128 rows
  const int nt   = swz & 3;
  const int col0 = nt << 7;

  const int t  = threadIdx.x;
  const int l  = t & 63;
  const int w  = t >> 6;          // 4 waves, 2M x 2N
  const int wm = (w >> 1) << 6;
  const int wn = (w & 1) << 6;
  const int lr = l & 15;
  const int lg = l >> 4;

  // --- staging maps ---
  // A (fp32): load q in 0..3: row = w*32 + q*8 + (l>>3), fp32 cols (l&7)*4..+3
  //   (8 lanes x 16B = one full 128B row per instruction -> perfectly coalesced)
  const float* gA = A + (size_t)(row0 + w * 32 + (l >> 3)) * D_ + ((l & 7) << 2);
  // B (bf16): load q in 0..1: row = w*32 + q*16 + (l>>2), bf16 cols (l&3)*8..+7
  const unsigned short* gB = Bw + (size_t)(col0 + w * 32 + (l >> 2)) * D_ + ((l & 3) << 3);

  // LDS write slots (16B granules, 4 per 64B row; phys = logical ^ ((row>>1)&3))
  // A: logical slot (l&7)>>1, f_A = (l>>4)&3 (uniform over q since q*8 rows)
  const int sA = (((l & 7) >> 1) ^ ((l >> 4) & 3));
  const int eA0 = (w * 32 + (l >> 3)) * 32 + sA * 8 + (l & 1) * 4;  // ushort idx, +q*256
  // B: logical slot l&3, f_B = (l>>3)&3 (uniform over q since q*16 rows)
  const int sB = ((l & 3) ^ ((l >> 3) & 3));
  const int eB0 = (w * 32 + (l >> 2)) * 32 + sB * 8;                // +q*512

  // read-side: logical slot lg of row r at phys lg ^ ((r>>1)&3); wm/wn/mi*16
  // are multiples of 16 so only lr enters the XOR.
  const int rs = (lg ^ ((lr >> 1) & 3)) << 3;

  f32x4  rA0, rA1, rA2, rA3;
  bf16x8 rB0, rB1;

#define LOAD(kk) do {                                   \
    const float* a_ = gA + ((kk) << 5);                 \
    rA0 = *(const f32x4*)(a_);                          \
    rA1 = *(const f32x4*)(a_ + 8 * D_);                 \
    rA2 = *(const f32x4*)(a_ + 16 * D_);                \
    rA3 = *(const f32x4*)(a_ + 24 * D_);                \
    const unsigned short* b_ = gB + ((kk) << 5);        \
    rB0 = *(const bf16x8*)(b_);                         \
    rB1 = *(const bf16x8*)(b_ + 16 * D_);               \
  } while (0)

#define WRITE(bf) do {                                                  \
    u32x2 p0 = {cvtpk(rA0[0], rA0[1]), cvtpk(rA0[2], rA0[3])};          \
    u32x2 p1 = {cvtpk(rA1[0], rA1[1]), cvtpk(rA1[2], rA1[3])};          \
    u32x2 p2 = {cvtpk(rA2[0], rA2[1]), cvtpk(rA2[2], rA2[3])};          \
    u32x2 p3 = {cvtpk(rA3[0], rA3[1]), cvtpk(rA3[2], rA3[3])};          \
    *(u32x2*)&ldsA[bf][eA0]       = p0;                                 \
    *(u32x2*)&ldsA[bf][eA0 + 256] = p1;                                 \
    *(u32x2*)&ldsA[bf][eA0 + 512] = p2;                                 \
    *(u32x2*)&ldsA[bf][eA0 + 768] = p3;                                 \
    *(bf16x8*)&ldsB[bf][eB0]       = rB0;                               \
    *(bf16x8*)&ldsB[bf][eB0 + 512] = rB1;                               \
  } while (0)

  f32x4 acc[4][4];
  const f32x4 z = {0.f, 0.f, 0.f, 0.f};
#pragma unroll
  for (int mi = 0; mi < 4; ++mi)
#pragma unroll
    for (int ni = 0; ni < 4; ++ni) acc[mi][ni] = z;

  LOAD(0);
  WRITE(0);
  LOAD(1);

  for (int kt = 0; kt < 16; ++kt) {
    const int bf = kt & 1;
    asm volatile("s_waitcnt lgkmcnt(0)" ::: "memory");  // own ds ops retired
    barrier_raw();                                      // buf[bf] ready block-wide

    bf16x8 af[4], bq[4];
#pragma unroll
    for (int mi = 0; mi < 4; ++mi)
      af[mi] = *(const bf16x8*)&ldsA[bf][(wm + mi * 16 + lr) * 32 + rs];
#pragma unroll
    for (int ni = 0; ni < 4; ++ni)
      bq[ni] = *(const bf16x8*)&ldsB[bf][(wn + ni * 16 + lr) * 32 + rs];

    if (kt + 1 < 16) WRITE(bf ^ 1);    // stage tile kt+1 (waits own loads only)
    if (kt + 2 < 16) LOAD(kt + 2);     // next loads fly under MFMA

    __builtin_amdgcn_s_setprio(1);
#pragma unroll
    for (int mi = 0; mi < 4; ++mi)
#pragma unroll
      for (int ni = 0; ni < 4; ++ni)
        acc[mi][ni] = __builtin_amdgcn_mfma_f32_16x16x32_bf16(
            af[mi], bq[ni], acc[mi][ni], 0, 0, 0);
    __builtin_amdgcn_s_setprio(0);
  }
#undef LOAD
#undef WRITE

  // fused ui partials over this block's 128 columns; atomic-free.
  // C/D layout: col = lr, row = lg*4 + j within each 16x16 frag.
  const int b = row0 >> 11;   // BM=128 divides S=2048 -> block-uniform batch
  float uacc[4][4];
#pragma unroll
  for (int mi = 0; mi < 4; ++mi)
#pragma unroll
    for (int j = 0; j < 4; ++j) uacc[mi][j] = 0.f;

#pragma unroll
  for (int ni = 0; ni < 4; ++ni) {
    const int gc = col0 + wn + ni * 16 + lr;
    const float vv = V[gc];
    const float base = di[b * H_ + gc] + be[gc];
#pragma unroll
    for (int mi = 0; mi < 4; ++mi)
#pragma unroll
      for (int j = 0; j < 4; ++j)
        uacc[mi][j] += vv * fast_tanh(base + acc[mi][ni][j]);
  }
  // reduce across the 16 lr-lanes; lanes lr==0 (lg=0..3) hold 4-row sums
#pragma unroll
  for (int mi = 0; mi < 4; ++mi)
#pragma unroll
    for (int j = 0; j < 4; ++j) {
      float s = uacc[mi][j];
      s += __shfl_xor(s, 1);
      s += __shfl_xor(s, 2);
      s += __shfl_xor(s, 4);
      s += __shfl_xor(s, 8);
      if (lr == 0) ured[w][mi * 16 + (lg << 2) + j] = s;
    }
  __syncthreads();
  if (t < 128) {
    const int r = t & 63, half = t >> 6;   // half 0: waves 0+1 (rows 0-63); 1: waves 2+3
    ui4[nt * (B_ * S_) + row0 + half * 64 + r] =
        ured[half * 2][r] + ured[half * 2 + 1][r];
  }
}

// ---------------------------------------------------------------------------
// softmax over S per batch row: sums the 4 ui partials, applies mask -> -inf.
// Mask dtype (bool-bytes vs int32) detected per block from word high-bytes
// (scan limited to first 128KB so it is in-bounds under both layouts).
__global__ void k_softmax(const float* __restrict__ ui4, const void* __restrict__ mask,
                          float* __restrict__ alpha) {
  __shared__ float red[4];
  __shared__ int sfl;
  const int b = blockIdx.x, t = threadIdx.x;
  const int l = t & 63, w = t >> 6;

  if (t == 0) sfl = 0;
  const unsigned int* mw = (const unsigned int*)mask;
  unsigned det = (mw[b * 512 + t] | mw[b * 512 + 256 + t]) & 0xFFFFFF00u;
  __syncthreads();
  if (det) atomicOr(&sfl, 1);
  __syncthreads();
  const int fl = sfl;   // 1 => byte layout

  float u[8];
#pragma unroll
  for (int i = 0; i < 8; ++i) {
    const int idx = b * S_ + t + i * 256;
    const int msk = fl ? (int)((const unsigned char*)mask)[idx]
                       : ((const int*)mask)[idx];
    const float uv = ui4[idx] + ui4[idx + B_ * S_] + ui4[idx + 2 * B_ * S_] +
                     ui4[idx + 3 * B_ * S_];
    u[i] = msk ? -__builtin_inff() : uv;
  }

  float mx = u[0];
#pragma unroll
  for (int i = 1; i < 8; ++i) mx = fmaxf(mx, u[i]);
#pragma unroll
  for (int off = 32; off; off >>= 1) mx = fmaxf(mx, __shfl_xor(mx, off));
  if (l == 0) red[w] = mx;
  __syncthreads();
  mx = fmaxf(fmaxf(red[0], red[1]), fmaxf(red[2], red[3]));
  __syncthreads();

  float p[8];
  float s = 0.f;
#pragma unroll
  for (int i = 0; i < 8; ++i) {
    p[i] = __builtin_amdgcn_exp2f((u[i] - mx) * 1.4426950408889634f);
    s += p[i];
  }
#pragma unroll
  for (int off = 32; off; off >>= 1) s += __shfl_xor(s, off);
  if (l == 0) red[w] = s;
  __syncthreads();
  s = red[0] + red[1] + red[2] + red[3];

  const float inv = 1.0f / s;
#pragma unroll
  for (int i = 0; i < 8; ++i) alpha[b * S_ + t + i * 256] = p[i] * inv;
}

// ---------------------------------------------------------------------------
// part[chunk][b][d] = sum over 128 s of alpha * ctx (fp32, L3-warm from gemm)
__global__ void k_wsum(const float* __restrict__ ctx, const float* __restrict__ alpha,
                       float* __restrict__ part) {
  __shared__ float red[3][512];
  const int b = blockIdx.x >> 4, chunk = blockIdx.x & 15;
  const int t = threadIdx.x;
  const int h0 = (t & 63) << 3;
  const int sw = t >> 6;
  const int s0 = chunk << 7;

  float acc[8] = {0.f, 0.f, 0.f, 0.f, 0.f, 0.f, 0.f, 0.f};
#pragma unroll 2
  for (int k = 0; k < 32; ++k) {
    const int s = s0 + sw + (k << 2);
    const float a = alpha[b * S_ + s];
    const f32x4* e = (const f32x4*)(ctx + ((size_t)(b * S_ + s)) * D_ + h0);
    f32x4 e0 = e[0], e1 = e[1];
#pragma unroll
    for (int j = 0; j < 4; ++j) acc[j] += a * e0[j];
#pragma unroll
    for (int j = 0; j < 4; ++j) acc[4 + j] += a * e1[j];
  }
  if (sw) {
#pragma unroll
    for (int j = 0; j < 8; ++j) red[sw - 1][h0 + j] = acc[j];
  }
  __syncthreads();
  if (sw == 0) {
#pragma unroll
    for (int j = 0; j < 8; ++j)
      part[((chunk << 6) + b) * 512 + h0 + j] =
          acc[j] + red[0][h0 + j] + red[1][h0 + j] + red[2][h0 + j];
  }
}

// ---------------------------------------------------------------------------
// k_tail: one block per b (512 thr). Phase 1: collapse 16 part chunks into
// LDS wsum. Phase 2: out1[b,h] = wsum.We[h,:] + be[h] (We from L2/L3).
__global__ void k_tail(const float* __restrict__ part, const float* __restrict__ We,
                       const float* __restrict__ be, float* __restrict__ out1) {
  __shared__ float wsum_s[512];
  const int b = blockIdx.x, t = threadIdx.x;

  float s = 0.f;
#pragma unroll
  for (int c = 0; c < 16; ++c) s += part[((c << 6) + b) * 512 + t];
  wsum_s[t] = s;
  __syncthreads();

  const f32x4* wp = (const f32x4*)wsum_s;
  const f32x4* ep = (const f32x4*)(We + (size_t)t * D_);
  float acc = 0.f;
#pragma unroll 8
  for (int i = 0; i < D_ / 4; ++i) {
    f32x4 x = wp[i], y = ep[i];
    acc += x[0] * y[0] + x[1] * y[1] + x[2] * y[2] + x[3] * y[3];
  }
  out1[b * H_ + t] = acc + be[t];
}

// ---------------------------------------------------------------------------
extern "C" void kernel_launch(void* const* d_in, const int* in_sizes, int n_in,
                              void* d_out, int out_size, void* d_ws, size_t ws_size,
                              hipStream_t stream) {
  const float* hidden = (const float*)d_in[0];
  const float* ctx    = (const float*)d_in[1];
  const void*  mask   = d_in[2];
  const float* Wd     = (const float*)d_in[3];
  const float* bd     = (const float*)d_in[4];
  const float* We     = (const float*)d_in[5];
  const float* be     = (const float*)d_in[6];
  const float* V      = (const float*)d_in[7];

  float* out   = (float*)d_out;
  float* alpha = out;               // [B,S]
  float* out1  = out + B_ * S_;     // [B,H]

  // ws layout (no ctx copy anymore — gemm reads fp32 ctx directly):
  //   [0, 2MB)   ui4 (gemm->softmax), then part (wsum->tail)
  //   [+128KB)   di (prep->gemm)
  //   [+512KB)   Web bf16
  char* ws = (char*)d_ws;
  const size_t off_u2  = 0;
  const size_t off_r3  = off_u2 + 4ull * B_ * S_ * 4;   // +2 MiB
  const size_t off_web = off_r3 + (size_t)B_ * H_ * 4;  // +128 KiB

  float* ui4  = (float*)(ws + off_u2);
  float* part = (float*)(ws + off_u2);
  float* di   = (float*)(ws + off_r3);
  unsigned short* Web = (unsigned short*)(ws + off_web);

  k_prep<<<256, 256, 0, stream>>>(hidden, Wd, bd, di, We, Web);
  k_ei_gemm<<<(B_ * S_ / 128) * 4, 256, 0, stream>>>(ctx, Web, be, V, di, ui4);
  k_softmax<<<B_, 256, 0, stream>>>(ui4, mask, alpha);
  k_wsum<<<B_ * 16, 256, 0, stream>>>(ctx, alpha, part);
  k_tail<<<B_, 512, 0, stream>>>(part, We, be, out1);
}

// Round 7
// 201.794 us; speedup vs baseline: 1.3047x; 1.0321x over previous
//
#include <hip/hip_runtime.h>
#include <cstdint>

// Problem constants (B,S,D,H) from the reference
#define B_ 64
#define S_ 2048
#define D_ 512
#define H_ 512

using f32x4  = __attribute__((ext_vector_type(4))) float;
using bf16x8 = __attribute__((ext_vector_type(8))) short;
using u32x2  = __attribute__((ext_vector_type(2))) unsigned int;

__device__ __forceinline__ unsigned short f2bf(float f) {
  unsigned u = __float_as_uint(f);
  u += 0x7FFFu + ((u >> 16) & 1u);   // round-to-nearest-even
  return (unsigned short)(u >> 16);
}
// packed f32x2 -> bf16x2 (RTE), hardware op (T12 primitive; no builtin on gfx950)
__device__ __forceinline__ unsigned int cvtpk(float lo, float hi) {
  unsigned int r;
  asm("v_cvt_pk_bf16_f32 %0, %1, %2" : "=v"(r) : "v"(lo), "v"(hi));
  return r;
}
// tanh via v_exp_f32: 1 - 2/(exp2(2x*log2e)+1); exact saturation at +-inf
__device__ __forceinline__ float fast_tanh(float x) {
  float t = __builtin_amdgcn_exp2f(x * 2.8853900817779268f);
  return 1.0f - 2.0f * __builtin_amdgcn_rcpf(t + 1.0f);
}

__device__ __forceinline__ void barrier_raw() {
  asm volatile("" ::: "memory");
  __builtin_amdgcn_s_barrier();
  asm volatile("" ::: "memory");
}

// ---------------------------------------------------------------------------
// k_prep: blocks [0,128): di[b,h] = hidden[b,:].Wd[h,:] + bd[h]
//         blocks [128,256): We fp32 -> bf16 (32768 chunks of 8)
__global__ void k_prep(const float* __restrict__ hidden, const float* __restrict__ Wd,
                       const float* __restrict__ bd, float* __restrict__ di,
                       const float* __restrict__ We, unsigned short* __restrict__ Web) {
  if (blockIdx.x < 128) {
    int idx = blockIdx.x * 256 + threadIdx.x;   // 32768 total
    int h = idx >> 6;
    int b = idx & 63;
    const f32x4* hp = (const f32x4*)(hidden + (size_t)b * D_);
    const f32x4* wp = (const f32x4*)(Wd + (size_t)h * D_);
    float acc = 0.f;
#pragma unroll 8
    for (int i = 0; i < D_ / 4; ++i) {
      f32x4 x = hp[i], y = wp[i];
      acc += x[0] * y[0] + x[1] * y[1] + x[2] * y[2] + x[3] * y[3];
    }
    di[b * H_ + h] = acc + bd[h];
  } else {
    int i = (blockIdx.x - 128) * 256 + threadIdx.x;   // 32768 chunks
    const f32x4* p = (const f32x4*)(We + (size_t)i * 8);
    f32x4 a = p[0], b = p[1];
    bf16x8 o;
    o[0] = (short)f2bf(a[0]); o[1] = (short)f2bf(a[1]);
    o[2] = (short)f2bf(a[2]); o[3] = (short)f2bf(a[3]);
    o[4] = (short)f2bf(b[0]); o[5] = (short)f2bf(b[1]);
    o[6] = (short)f2bf(b[2]); o[7] = (short)f2bf(b[3]);
    *(bf16x8*)(Web + (size_t)i * 8) = o;
  }
}

// ---------------------------------------------------------------------------
// ei-GEMM, fp32 A read directly; reg-staged A with in-register
// v_cvt_pk_bf16_f32, reg-staged bf16 B. Fused ui partials.
// Tile 128x128, 4 waves (2x2), BK=32, 16 k-steps, 33KB LDS, 3 blocks/CU.
// Deep pipeline with TWO named register sets (a/b) so the ds_write's vmcnt
// dependency is ~2 iterations old, and the MFMA cluster issues BEFORE the
// writes (the R6 bottleneck: MFMAs were stuck behind the write-side vmcnt):
//   iter kt: lgkmcnt(0); barrier           // buf[kt&1] visible block-wide
//            ds_read frags(buf[kt&1])
//            LOAD(kt+2) -> set[kt&1]       // 2-iteration slack to its WRITE
//            setprio(1); 16 MFMA; setprio(0)
//            WRITE(buf[kt&1^1]) <- set[kt&1^1]   // tile kt+1
// XOR slot swizzle (16B slots, phys = logical ^ ((row>>1)&3)) on both the
// ds_write and ds_read sides -> 2-way banks everywhere (free, m136).
__global__ __launch_bounds__(256, 3) void k_ei_gemm(
    const float* __restrict__ A, const unsigned short* __restrict__ Bw,
    const float* __restrict__ be, const float* __restrict__ V,
    const float* __restrict__ di, float* __restrict__ ui4) {
  __shared__ __align__(16) unsigned short ldsA[2][128 * 32];   // 8KB each
  __shared__ __align__(16) unsigned short ldsB[2][128 * 32];
  __shared__ float ured[4][64];

  const int bid = blockIdx.x;
  const int swz = (bid & 7) * 512 + (bid >> 3);   // bijective XCD chunking (4096%8==0)
  const int row0 = (swz >> 2) << 7;               // 1024 m-tiles of 128 rows
  const int nt   = swz & 3;
  const int col0 = nt << 7;

  const int t  = threadIdx.x;
  const int l  = t & 63;
  const int w  = t >> 6;          // 4 waves, 2M x 2N
  const int wm = (w >> 1) << 6;
  const int wn = (w & 1) << 6;
  const int lr = l & 15;
  const int lg = l >> 4;

  // --- staging maps ---
  // A (fp32): load q in 0..3: row = w*32 + q*8 + (l>>3), fp32 cols (l&7)*4..+3
  const float* gA = A + (size_t)(row0 + w * 32 + (l >> 3)) * D_ + ((l & 7) << 2);
  // B (bf16): load q in 0..1: row = w*32 + q*16 + (l>>2), bf16 cols (l&3)*8..+7
  const unsigned short* gB = Bw + (size_t)(col0 + w * 32 + (l >> 2)) * D_ + ((l & 3) << 3);

  // LDS write slots (16B granules, 4 per 64B row; phys = logical ^ ((row>>1)&3))
  const int sA = (((l & 7) >> 1) ^ ((l >> 4) & 3));
  const int eA0 = (w * 32 + (l >> 3)) * 32 + sA * 8 + (l & 1) * 4;  // ushort idx, +q*256
  const int sB = ((l & 3) ^ ((l >> 3) & 3));
  const int eB0 = (w * 32 + (l >> 2)) * 32 + sB * 8;                // +q*512

  // read-side: logical slot lg of row r at phys lg ^ ((r>>1)&3)
  const int rs = (lg ^ ((lr >> 1) & 3)) << 3;

  // two named staging register sets (rule #20: never runtime-index these)
  f32x4  rA0a, rA1a, rA2a, rA3a;  bf16x8 rB0a, rB1a;
  f32x4  rA0b, rA1b, rA2b, rA3b;  bf16x8 rB0b, rB1b;

#define LOADN(S, kk) do {                               \
    const float* a_ = gA + ((kk) << 5);                 \
    rA0##S = *(const f32x4*)(a_);                       \
    rA1##S = *(const f32x4*)(a_ + 8 * D_);              \
    rA2##S = *(const f32x4*)(a_ + 16 * D_);             \
    rA3##S = *(const f32x4*)(a_ + 24 * D_);             \
    const unsigned short* b_ = gB + ((kk) << 5);        \
    rB0##S = *(const bf16x8*)(b_);                      \
    rB1##S = *(const bf16x8*)(b_ + 16 * D_);            \
  } while (0)

#define WRITEN(S, bf) do {                                                  \
    u32x2 p0 = {cvtpk(rA0##S[0], rA0##S[1]), cvtpk(rA0##S[2], rA0##S[3])};  \
    u32x2 p1 = {cvtpk(rA1##S[0], rA1##S[1]), cvtpk(rA1##S[2], rA1##S[3])};  \
    u32x2 p2 = {cvtpk(rA2##S[0], rA2##S[1]), cvtpk(rA2##S[2], rA2##S[3])};  \
    u32x2 p3 = {cvtpk(rA3##S[0], rA3##S[1]), cvtpk(rA3##S[2], rA3##S[3])};  \
    *(u32x2*)&ldsA[bf][eA0]       = p0;                                     \
    *(u32x2*)&ldsA[bf][eA0 + 256] = p1;                                     \
    *(u32x2*)&ldsA[bf][eA0 + 512] = p2;                                     \
    *(u32x2*)&ldsA[bf][eA0 + 768] = p3;                                     \
    *(bf16x8*)&ldsB[bf][eB0]       = rB0##S;                                \
    *(bf16x8*)&ldsB[bf][eB0 + 512] = rB1##S;                                \
  } while (0)

  f32x4 acc[4][4];
  const f32x4 z = {0.f, 0.f, 0.f, 0.f};
#pragma unroll
  for (int mi = 0; mi < 4; ++mi)
#pragma unroll
    for (int ni = 0; ni < 4; ++ni) acc[mi][ni] = z;

// KBODY: one k-step. LD / WR are statements (or nothing).
#define KBODY(bf, LD, WR) do {                                              \
    asm volatile("s_waitcnt lgkmcnt(0)" ::: "memory");                      \
    barrier_raw();                                                          \
    bf16x8 af[4], bq[4];                                                    \
    _Pragma("unroll") for (int mi = 0; mi < 4; ++mi)                        \
      af[mi] = *(const bf16x8*)&ldsA[bf][(wm + mi * 16 + lr) * 32 + rs];    \
    _Pragma("unroll") for (int ni = 0; ni < 4; ++ni)                        \
      bq[ni] = *(const bf16x8*)&ldsB[bf][(wn + ni * 16 + lr) * 32 + rs];    \
    LD;                                                                     \
    __builtin_amdgcn_s_setprio(1);                                          \
    _Pragma("unroll") for (int mi = 0; mi < 4; ++mi)                        \
      _Pragma("unroll") for (int ni = 0; ni < 4; ++ni)                      \
        acc[mi][ni] = __builtin_amdgcn_mfma_f32_16x16x32_bf16(              \
            af[mi], bq[ni], acc[mi][ni], 0, 0, 0);                          \
    __builtin_amdgcn_s_setprio(0);                                          \
    WR;                                                                     \
  } while (0)

  // prologue: tile0 -> set a -> buf0; tile1 -> set b
  LOADN(a, 0);
  WRITEN(a, 0);
  LOADN(b, 1);

  for (int u = 0; u < 7; ++u) {
    const int kt = 2 * u;
    KBODY(0, LOADN(a, kt + 2), WRITEN(b, 1));   // read buf0; tile kt+2 -> a; write tile kt+1
    KBODY(1, LOADN(b, kt + 3), WRITEN(a, 0));   // read buf1; tile kt+3 -> b; write tile kt+2
  }
  KBODY(0, (void)0, WRITEN(b, 1));              // kt=14: write tile15
  KBODY(1, (void)0, (void)0);                   // kt=15
#undef KBODY
#undef LOADN
#undef WRITEN

  // fused ui partials over this block's 128 columns; atomic-free.
  // C/D layout: col = lr, row = lg*4 + j within each 16x16 frag.
  const int b = row0 >> 11;   // BM=128 divides S=2048 -> block-uniform batch
  float uacc[4][4];
#pragma unroll
  for (int mi = 0; mi < 4; ++mi)
#pragma unroll
    for (int j = 0; j < 4; ++j) uacc[mi][j] = 0.f;

#pragma unroll
  for (int ni = 0; ni < 4; ++ni) {
    const int gc = col0 + wn + ni * 16 + lr;
    const float vv = V[gc];
    const float base = di[b * H_ + gc] + be[gc];
#pragma unroll
    for (int mi = 0; mi < 4; ++mi)
#pragma unroll
      for (int j = 0; j < 4; ++j)
        uacc[mi][j] += vv * fast_tanh(base + acc[mi][ni][j]);
  }
  // reduce across the 16 lr-lanes; lanes lr==0 (lg=0..3) hold 4-row sums
#pragma unroll
  for (int mi = 0; mi < 4; ++mi)
#pragma unroll
    for (int j = 0; j < 4; ++j) {
      float s = uacc[mi][j];
      s += __shfl_xor(s, 1);
      s += __shfl_xor(s, 2);
      s += __shfl_xor(s, 4);
      s += __shfl_xor(s, 8);
      if (lr == 0) ured[w][mi * 16 + (lg << 2) + j] = s;
    }
  __syncthreads();
  if (t < 128) {
    const int r = t & 63, half = t >> 6;   // half 0: waves 0+1 (rows 0-63); 1: waves 2+3
    ui4[nt * (B_ * S_) + row0 + half * 64 + r] =
        ured[half * 2][r] + ured[half * 2 + 1][r];
  }
}

// ---------------------------------------------------------------------------
// softmax over S per batch row: sums the 4 ui partials, applies mask -> -inf.
// Mask dtype (bool-bytes vs int32) detected per block from word high-bytes
// (scan limited to first 128KB so it is in-bounds under both layouts).
__global__ void k_softmax(const float* __restrict__ ui4, const void* __restrict__ mask,
                          float* __restrict__ alpha) {
  __shared__ float red[4];
  __shared__ int sfl;
  const int b = blockIdx.x, t = threadIdx.x;
  const int l = t & 63, w = t >> 6;

  if (t == 0) sfl = 0;
  const unsigned int* mw = (const unsigned int*)mask;
  unsigned det = (mw[b * 512 + t] | mw[b * 512 + 256 + t]) & 0xFFFFFF00u;
  __syncthreads();
  if (det) atomicOr(&sfl, 1);
  __syncthreads();
  const int fl = sfl;   // 1 => byte layout

  float u[8];
#pragma unroll
  for (int i = 0; i < 8; ++i) {
    const int idx = b * S_ + t + i * 256;
    const int msk = fl ? (int)((const unsigned char*)mask)[idx]
                       : ((const int*)mask)[idx];
    const float uv = ui4[idx] + ui4[idx + B_ * S_] + ui4[idx + 2 * B_ * S_] +
                     ui4[idx + 3 * B_ * S_];
    u[i] = msk ? -__builtin_inff() : uv;
  }

  float mx = u[0];
#pragma unroll
  for (int i = 1; i < 8; ++i) mx = fmaxf(mx, u[i]);
#pragma unroll
  for (int off = 32; off; off >>= 1) mx = fmaxf(mx, __shfl_xor(mx, off));
  if (l == 0) red[w] = mx;
  __syncthreads();
  mx = fmaxf(fmaxf(red[0], red[1]), fmaxf(red[2], red[3]));
  __syncthreads();

  float p[8];
  float s = 0.f;
#pragma unroll
  for (int i = 0; i < 8; ++i) {
    p[i] = __builtin_amdgcn_exp2f((u[i] - mx) * 1.4426950408889634f);
    s += p[i];
  }
#pragma unroll
  for (int off = 32; off; off >>= 1) s += __shfl_xor(s, off);
  if (l == 0) red[w] = s;
  __syncthreads();
  s = red[0] + red[1] + red[2] + red[3];

  const float inv = 1.0f / s;
#pragma unroll
  for (int i = 0; i < 8; ++i) alpha[b * S_ + t + i * 256] = p[i] * inv;
}

// ---------------------------------------------------------------------------
// part[chunk][b][d] = sum over 128 s of alpha * ctx (fp32, L3-warm from gemm)
__global__ void k_wsum(const float* __restrict__ ctx, const float* __restrict__ alpha,
                       float* __restrict__ part) {
  __shared__ float red[3][512];
  const int b = blockIdx.x >> 4, chunk = blockIdx.x & 15;
  const int t = threadIdx.x;
  const int h0 = (t & 63) << 3;
  const int sw = t >> 6;
  const int s0 = chunk << 7;

  float acc[8] = {0.f, 0.f, 0.f, 0.f, 0.f, 0.f, 0.f, 0.f};
#pragma unroll 2
  for (int k = 0; k < 32; ++k) {
    const int s = s0 + sw + (k << 2);
    const float a = alpha[b * S_ + s];
    const f32x4* e = (const f32x4*)(ctx + ((size_t)(b * S_ + s)) * D_ + h0);
    f32x4 e0 = e[0], e1 = e[1];
#pragma unroll
    for (int j = 0; j < 4; ++j) acc[j] += a * e0[j];
#pragma unroll
    for (int j = 0; j < 4; ++j) acc[4 + j] += a * e1[j];
  }
  if (sw) {
#pragma unroll
    for (int j = 0; j < 8; ++j) red[sw - 1][h0 + j] = acc[j];
  }
  __syncthreads();
  if (sw == 0) {
#pragma unroll
    for (int j = 0; j < 8; ++j)
      part[((chunk << 6) + b) * 512 + h0 + j] =
          acc[j] + red[0][h0 + j] + red[1][h0 + j] + red[2][h0 + j];
  }
}

// ---------------------------------------------------------------------------
// k_tail: one block per b (512 thr). Phase 1: collapse 16 part chunks into
// LDS wsum. Phase 2: out1[b,h] = wsum.We[h,:] + be[h] (We from L2/L3).
__global__ void k_tail(const float* __restrict__ part, const float* __restrict__ We,
                       const float* __restrict__ be, float* __restrict__ out1) {
  __shared__ float wsum_s[512];
  const int b = blockIdx.x, t = threadIdx.x;

  float s = 0.f;
#pragma unroll
  for (int c = 0; c < 16; ++c) s += part[((c << 6) + b) * 512 + t];
  wsum_s[t] = s;
  __syncthreads();

  const f32x4* wp = (const f32x4*)wsum_s;
  const f32x4* ep = (const f32x4*)(We + (size_t)t * D_);
  float acc = 0.f;
#pragma unroll 8
  for (int i = 0; i < D_ / 4; ++i) {
    f32x4 x = wp[i], y = ep[i];
    acc += x[0] * y[0] + x[1] * y[1] + x[2] * y[2] + x[3] * y[3];
  }
  out1[b * H_ + t] = acc + be[t];
}

// ---------------------------------------------------------------------------
extern "C" void kernel_launch(void* const* d_in, const int* in_sizes, int n_in,
                              void* d_out, int out_size, void* d_ws, size_t ws_size,
                              hipStream_t stream) {
  const float* hidden = (const float*)d_in[0];
  const float* ctx    = (const float*)d_in[1];
  const void*  mask   = d_in[2];
  const float* Wd     = (const float*)d_in[3];
  const float* bd     = (const float*)d_in[4];
  const float* We     = (const float*)d_in[5];
  const float* be     = (const float*)d_in[6];
  const float* V      = (const float*)d_in[7];

  float* out   = (float*)d_out;
  float* alpha = out;               // [B,S]
  float* out1  = out + B_ * S_;     // [B,H]

  // ws layout (no ctx copy — gemm reads fp32 ctx directly):
  //   [0, 2MB)   ui4 (gemm->softmax), then part (wsum->tail)
  //   [+128KB)   di (prep->gemm)
  //   [+512KB)   Web bf16
  char* ws = (char*)d_ws;
  const size_t off_u2  = 0;
  const size_t off_r3  = off_u2 + 4ull * B_ * S_ * 4;   // +2 MiB
  const size_t off_web = off_r3 + (size_t)B_ * H_ * 4;  // +128 KiB

  float* ui4  = (float*)(ws + off_u2);
  float* part = (float*)(ws + off_u2);
  float* di   = (float*)(ws + off_r3);
  unsigned short* Web = (unsigned short*)(ws + off_web);

  k_prep<<<256, 256, 0, stream>>>(hidden, Wd, bd, di, We, Web);
  k_ei_gemm<<<(B_ * S_ / 128) * 4, 256, 0, stream>>>(ctx, Web, be, V, di, ui4);
  k_softmax<<<B_, 256, 0, stream>>>(ui4, mask, alpha);
  k_wsum<<<B_ * 16, 256, 0, stream>>>(ctx, alpha, part);
  k_tail<<<B_, 512, 0, stream>>>(part, We, be, out1);
}